// Round 1
// baseline (213.322 us; speedup 1.0000x reference)
//
#include <hip/hip_runtime.h>

#define NSEG 16

__global__ __launch_bounds__(256) void plac_kernel(
    const float* __restrict__ x,
    const int* __restrict__ bps,        // 15 sorted interior breakpoints (Q16.16)
    const int* __restrict__ intercepts, // 16
    const int* __restrict__ signs,      // 16, in {-1,+1}
    const int* __restrict__ exps,       // 16, in [0,8)
    float* __restrict__ out,
    long long n4,                       // number of float4 packets
    long long n)                        // total elements
{
    __shared__ int s_bp[15];
    __shared__ int s_b[NSEG];
    __shared__ int s_s[NSEG];
    __shared__ int s_e[NSEG];

    const int tid = threadIdx.x;
    if (tid < 15) s_bp[tid] = bps[tid];
    if (tid < NSEG) {
        s_b[tid] = intercepts[tid];
        s_s[tid] = signs[tid];
        s_e[tid] = exps[tid];
    }
    __syncthreads();

    long long idx    = (long long)blockIdx.x * blockDim.x + tid;
    long long stride = (long long)gridDim.x * blockDim.x;

    const float4* __restrict__ x4 = (const float4*)x;
    float4* __restrict__ o4 = (float4*)out;

    for (long long i = idx; i < n4; i += stride) {
        float4 v = x4[i];
        float4 r;
        float* vp = reinterpret_cast<float*>(&v);
        float* rp = reinterpret_cast<float*>(&r);
        #pragma unroll
        for (int j = 0; j < 4; ++j) {
            int xq = (int)(vp[j] * 65536.0f);
            int seg = 0;
            #pragma unroll
            for (int k = 0; k < 15; ++k) seg += (xq >= s_bp[k]);
            int y = s_b[seg] + s_s[seg] * (xq >> s_e[seg]);
            rp[j] = (float)y * (1.0f / 65536.0f);
        }
        o4[i] = r;
    }

    // Scalar tail (n not divisible by 4) — handled by block 0 only.
    if (blockIdx.x == 0) {
        long long base = n4 * 4;
        for (long long i = base + tid; i < n; i += blockDim.x) {
            int xq = (int)(x[i] * 65536.0f);
            int seg = 0;
            #pragma unroll
            for (int k = 0; k < 15; ++k) seg += (xq >= s_bp[k]);
            int y = s_b[seg] + s_s[seg] * (xq >> s_e[seg]);
            out[i] = (float)y * (1.0f / 65536.0f);
        }
    }
}

extern "C" void kernel_launch(void* const* d_in, const int* in_sizes, int n_in,
                              void* d_out, int out_size, void* d_ws, size_t ws_size,
                              hipStream_t stream) {
    const float* x          = (const float*)d_in[0];
    const int*   bps        = (const int*)d_in[1];
    const int*   intercepts = (const int*)d_in[2];
    const int*   signs      = (const int*)d_in[3];
    const int*   exps       = (const int*)d_in[4];
    float* out = (float*)d_out;

    long long n  = (long long)out_size;
    long long n4 = n / 4;

    const int block = 256;
    long long blocks_needed = (n4 + block - 1) / block;
    int grid = (int)((blocks_needed < 2048) ? (blocks_needed > 0 ? blocks_needed : 1)
                                            : 2048);

    plac_kernel<<<grid, block, 0, stream>>>(x, bps, intercepts, signs, exps,
                                            out, n4, n);
}